// Round 15
// baseline (127.677 us; speedup 1.0000x reference)
//
#include <hip/hip_runtime.h>

typedef unsigned short u16;
typedef unsigned int u32;
typedef __bf16 bf16;
typedef __bf16 bf16x8 __attribute__((ext_vector_type(8)));
typedef __bf16 bf16x4 __attribute__((ext_vector_type(4)));
typedef float f32x4 __attribute__((ext_vector_type(4)));

#define NSAMP 2048
#define KH 3
#define NNBR 16
#define F 128
#define OUT_O 256   // C_OUT * F_OUT
#define QT 384      // KH * F
#define SPB 4       // samples per (persistent) block
#define NBLK (NSAMP / SPB)   // 512 blocks = exactly 2 per CU

// LDS row stride MUST be a multiple of 8 elems (16 B) — misaligned b128 LDS
// ops get split by HW (R7). 136 elems = 272 B ok. 2-way bank aliasing of b128
// reads is the floor (16 lanes x 16B > 128B bank span) and is ~free (m136).
#define ZLD 136
#define YLD 136

__device__ __forceinline__ bf16x4 cvt4(float4 v) {
    bf16x4 h;
    h[0] = (bf16)v.x; h[1] = (bf16)v.y; h[2] = (bf16)v.z; h[3] = (bf16)v.w;
    return h;
}

__global__ void wprep(const float* __restrict__ W, bf16* __restrict__ Wbf) {
    int i = blockIdx.x * 256 + threadIdx.x;
    if (i < OUT_O * QT) Wbf[i] = (bf16)W[i];
}

// Persistent blocks: 512 blocks x 4 samples. Per-sample structure is exactly
// R8's (80.5us, no spill). Sample s's staging overlaps GEMM2/epilogue of s-1:
// Zs/xls/sls writers are safe after barB(q2,s-1) since all their readers
// finished before that barrier and GEMM2 reads only Ys / epilogue only regs.
__launch_bounds__(512, 4)
__global__ void featkhop(const float* __restrict__ xg,
                         const float* __restrict__ ng,
                         const bf16* __restrict__ Wbf,
                         float* __restrict__ out) {
    // Zs rows 0..48 = x + 48 neighbors (bf16); rows 49..63 read by MFMA as
    // don't-care garbage (their output rows are discarded); f32 scratch
    // aliases that tail, all barrier-ordered.
    __shared__ __align__(16) bf16 Zs[64 * ZLD];       // 17408 B
    __shared__ __align__(16) bf16 Ys[2][64 * YLD];    // 34816 B, ping-pong
    float* const xls = (float*)(Zs + 49 * ZLD);       // 128 f32 (byte 13328, 16B-aligned)
    float* const sls = xls + F;                        // [3][128] f32
    float* const rsi = xls + 4 * F;                    // 128 f32, per current q

    const int t = threadIdx.x;
    const int lane = t & 63;
    const int w = t >> 6;        // wave 0..7
    const int lr = lane & 15;
    const int lg = lane >> 4;

    const int a_row = w * 16 + lr;       // adjacency row this lane owns
    const int cbase = lg * 8;            // within-32 col offset
    const bf16* Wbase = Wbf + (size_t)(w * 32 + lr) * QT;

    for (int s = 0; s < SPB; ++s) {
        const int i = blockIdx.x + NBLK * s;   // streaming stripe across blocks

        // ---- stage x: fp32 to xls, bf16 to Z row 0 ----
        if (t < F / 4) {
            float4 v = *(const float4*)(xg + (size_t)i * F + t * 4);
            *(float4*)(xls + t * 4) = v;
            *(bf16x4*)(Zs + 0 * ZLD + t * 4) = cvt4(v);
        }
        // ---- stage neighbors: bf16 rows 1..48 ----
        const float* nb = ng + (size_t)i * (KH * NNBR * F);
        #pragma unroll
        for (int c = 0; c < 3; ++c) {
            int j = c * 512 + t;
            float4 v = *(const float4*)(nb + j * 4);
            int fl = j * 4;
            int row = 1 + (fl >> 7);     // neighbor 0..47 -> rows 1..48
            int b = fl & 127;
            *(bf16x4*)(Zs + row * ZLD + b) = cvt4(v);
        }
        // ---- s[q][b] = sum_n nbr[q][n][b], from GLOBAL f32 (L2-hot) ----
        if (t < KH * F) {
            int q = t >> 7, b = t & 127;
            float ssum = 0.f;
            #pragma unroll
            for (int n = 0; n < NNBR; ++n) ssum += nb[(q * NNBR + n) * F + b];
            sls[q * F + b] = ssum;
        }
        __syncthreads();                 // bar S(s): Zs/xls/sls ready

        const float x_a = xls[a_row];

        f32x4 acc2[4][2];
        {
            f32x4 zf = {0.f, 0.f, 0.f, 0.f};
            #pragma unroll
            for (int mt = 0; mt < 4; ++mt) { acc2[mt][0] = zf; acc2[mt][1] = zf; }
        }

        #pragma unroll
        for (int q = 0; q < KH; ++q) {
            // ---- build u-row ONCE in registers (bf16, 16 regs); rowsum ----
            const float s_a = sls[q * F + a_row];
            bf16x8 uvh[4];
            float ps = 0.f;
            #pragma unroll
            for (int kk = 0; kk < 4; ++kk) {
                float4 xb0 = *(const float4*)(xls + kk * 32 + cbase);
                float4 xb1 = *(const float4*)(xls + kk * 32 + cbase + 4);
                float4 sb0 = *(const float4*)(sls + q * F + kk * 32 + cbase);
                float4 sb1 = *(const float4*)(sls + q * F + kk * 32 + cbase + 4);
                float xb[8] = {xb0.x, xb0.y, xb0.z, xb0.w, xb1.x, xb1.y, xb1.z, xb1.w};
                float sb[8] = {sb0.x, sb0.y, sb0.z, sb0.w, sb1.x, sb1.y, sb1.z, sb1.w};
                #pragma unroll
                for (int e = 0; e < 8; ++e) {
                    float tv = x_a * sb[e] + xb[e] * s_a;
                    float r = tv * __builtin_amdgcn_rsqf(fmaxf(fabsf(tv), 1e-8f));
                    uvh[kk][e] = (bf16)r;
                    ps += fabsf(r);
                }
            }
            ps += __shfl_xor(ps, 16);    // reduce over the 4 lg-mates
            ps += __shfl_xor(ps, 32);
            if (lg == 0) rsi[a_row] = __builtin_amdgcn_rcpf(ps + 1e-7f);
            __syncthreads();             // bar A(q): rsi ready; Ys[q&1] free

            // ---- GEMM1 (swapped): Y^T = adj * Z^T; adj frag = A operand ----
            bf16* Ysb = Ys[q & 1];
            f32x4 acc1[4];
            {
                f32x4 zf = {0.f, 0.f, 0.f, 0.f};
                #pragma unroll
                for (int mt = 0; mt < 4; ++mt) acc1[mt] = zf;
            }
            #pragma unroll
            for (int kk = 0; kk < 4; ++kk) {
                float4 r0 = *(const float4*)(rsi + kk * 32 + cbase);
                float4 r1 = *(const float4*)(rsi + kk * 32 + cbase + 4);
                float rb[8] = {r0.x, r0.y, r0.z, r0.w, r1.x, r1.y, r1.z, r1.w};
                bf16x8 afrag;
                #pragma unroll
                for (int e = 0; e < 8; ++e)
                    afrag[e] = (bf16)((float)uvh[kk][e] * rb[e]);
                #pragma unroll
                for (int mt = 0; mt < 4; ++mt) {
                    bf16x8 zfrag = *(const bf16x8*)(Zs + (mt * 16 + lr) * ZLD + kk * 32 + cbase);
                    acc1[mt] = __builtin_amdgcn_mfma_f32_16x16x32_bf16(afrag, zfrag, acc1[mt], 0, 0, 0);
                }
            }

            // ---- prefetch W fragments for this q's GEMM2 (drained by bar B) ----
            bf16x8 wf0[4], wf1[4];
            #pragma unroll
            for (int kk = 0; kk < 4; ++kk) {
                const bf16* wp = Wbase + q * F + kk * 32 + cbase;
                wf0[kk] = *(const bf16x8*)wp;
                wf1[kk] = *(const bf16x8*)(wp + 16 * QT);
            }

            // D: col=lr -> v_local, row=lg*4+r -> a_local => lane holds
            // Y[v=mt*16+lr][a=w*16+lg*4+r], 4 consecutive a => b64 store.
            #pragma unroll
            for (int mt = 0; mt < 4; ++mt) {
                bf16x4 yv;
                #pragma unroll
                for (int r = 0; r < 4; ++r) yv[r] = (bf16)acc1[mt][r];
                *(bf16x4*)(Ysb + (mt * 16 + lr) * YLD + w * 16 + lg * 4) = yv;
            }
            __syncthreads();             // bar B(q): Ys[q&1] complete

            // ---- GEMM2 (q-slice): acc2 += Y_q(64x128) @ Wq^T ----
            #pragma unroll
            for (int kk = 0; kk < 4; ++kk) {
                #pragma unroll
                for (int mt = 0; mt < 4; ++mt) {
                    bf16x8 af = *(const bf16x8*)(Ysb + (mt * 16 + lr) * YLD + kk * 32 + cbase);
                    acc2[mt][0] = __builtin_amdgcn_mfma_f32_16x16x32_bf16(af, wf0[kk], acc2[mt][0], 0, 0, 0);
                    acc2[mt][1] = __builtin_amdgcn_mfma_f32_16x16x32_bf16(af, wf1[kk], acc2[mt][1], 0, 0, 0);
                }
            }
            // next q's Ys/rsi writes are barrier-ordered (bar A/B of q+1).
        }

        // ---- epilogue: row 0 -> x_out, rows 1..48 -> nbr_out ----
        // Stores drain while next sample's staging loads issue (no barrier
        // between them touches the same buffers).
        float* xout = out + (size_t)i * OUT_O;
        float* nout = out + (size_t)NSAMP * OUT_O + (size_t)i * 48 * OUT_O;
        #pragma unroll
        for (int mt = 0; mt < 4; ++mt) {
            #pragma unroll
            for (int r = 0; r < 4; ++r) {
                int v = mt * 16 + lg * 4 + r;
                #pragma unroll
                for (int nn = 0; nn < 2; ++nn) {
                    int o = w * 32 + nn * 16 + lr;
                    float val = acc2[mt][nn][r];
                    if (v == 0) xout[o] = val;
                    else if (v <= 48) nout[(size_t)(v - 1) * OUT_O + o] = val;
                }
            }
        }
    }
}

extern "C" void kernel_launch(void* const* d_in, const int* in_sizes, int n_in,
                              void* d_out, int out_size, void* d_ws, size_t ws_size,
                              hipStream_t stream) {
    const float* x   = (const float*)d_in[0];
    const float* nbr = (const float*)d_in[1];
    const float* W   = (const float*)d_in[2];
    bf16* Wbf = (bf16*)d_ws;   // 256*384 bf16 = 192 KiB
    wprep<<<(OUT_O * QT + 255) / 256, 256, 0, stream>>>(W, Wbf);
    featkhop<<<NBLK, 512, 0, stream>>>(x, nbr, Wbf, (float*)d_out);
}

// Round 16
// 92.688 us; speedup vs baseline: 1.3775x; 1.3775x over previous
//
#include <hip/hip_runtime.h>

typedef unsigned short u16;
typedef unsigned int u32;
typedef __bf16 bf16;
typedef __bf16 bf16x8 __attribute__((ext_vector_type(8)));
typedef __bf16 bf16x4 __attribute__((ext_vector_type(4)));
typedef float f32x4 __attribute__((ext_vector_type(4)));

#define NSAMP 2048
#define KH 3
#define NNBR 16
#define F 128
#define OUT_O 256   // C_OUT * F_OUT
#define QT 384      // KH * F

// LDS row stride MUST be a multiple of 8 elems (16 B) — misaligned b128 LDS
// ops get split by HW (R7). 136 elems = 272 B ok.
#define ZLD 136
#define YLD 136

__device__ __forceinline__ bf16x4 cvt4(float4 v) {
    bf16x4 h;
    h[0] = (bf16)v.x; h[1] = (bf16)v.y; h[2] = (bf16)v.z; h[3] = (bf16)v.w;
    return h;
}

__global__ void wprep(const float* __restrict__ W, bf16* __restrict__ Wbf) {
    int i = blockIdx.x * 256 + threadIdx.x;
    if (i < OUT_O * QT) Wbf[i] = (bf16)W[i];
}

// ---- pipeline stage helpers (all indices constant after inlining) ----

__device__ __forceinline__ void build_row(int q, const float* xls, const float* sls,
                                          float* rsb, bf16x8 uvh[4],
                                          float x_a, int a_row, int cbase, int lg) {
    const float s_a = sls[q * F + a_row];
    float ps = 0.f;
    #pragma unroll
    for (int kk = 0; kk < 4; ++kk) {
        float4 xb0 = *(const float4*)(xls + kk * 32 + cbase);
        float4 xb1 = *(const float4*)(xls + kk * 32 + cbase + 4);
        float4 sb0 = *(const float4*)(sls + q * F + kk * 32 + cbase);
        float4 sb1 = *(const float4*)(sls + q * F + kk * 32 + cbase + 4);
        float xb[8] = {xb0.x, xb0.y, xb0.z, xb0.w, xb1.x, xb1.y, xb1.z, xb1.w};
        float sb[8] = {sb0.x, sb0.y, sb0.z, sb0.w, sb1.x, sb1.y, sb1.z, sb1.w};
        #pragma unroll
        for (int e = 0; e < 8; ++e) {
            float tv = x_a * sb[e] + xb[e] * s_a;
            float r = tv * __builtin_amdgcn_rsqf(fmaxf(fabsf(tv), 1e-8f));
            uvh[kk][e] = (bf16)r;        // bf16: 16 regs cross-barrier
            ps += fabsf(r);
        }
    }
    ps += __shfl_xor(ps, 16);            // reduce over the 4 lg-mates
    ps += __shfl_xor(ps, 32);
    if (lg == 0) rsb[a_row] = __builtin_amdgcn_rcpf(ps + 1e-7f);
}

// mt-outer: acc1 is a single f32x4 (4 regs); afrag[4] (16 regs) built once.
__device__ __forceinline__ void gemm1_store(const bf16x8 uvh[4], const float* rsb,
                                            const bf16* Zs, bf16* Ysb,
                                            int lr, int lg, int w, int cbase) {
    bf16x8 afrag[4];
    #pragma unroll
    for (int kk = 0; kk < 4; ++kk) {
        float4 r0 = *(const float4*)(rsb + kk * 32 + cbase);
        float4 r1 = *(const float4*)(rsb + kk * 32 + cbase + 4);
        float rb[8] = {r0.x, r0.y, r0.z, r0.w, r1.x, r1.y, r1.z, r1.w};
        #pragma unroll
        for (int e = 0; e < 8; ++e)
            afrag[kk][e] = (bf16)((float)uvh[kk][e] * rb[e]);
    }
    #pragma unroll
    for (int mt = 0; mt < 4; ++mt) {
        f32x4 a1 = {0.f, 0.f, 0.f, 0.f};
        #pragma unroll
        for (int kk = 0; kk < 4; ++kk) {
            bf16x8 zfrag = *(const bf16x8*)(Zs + (mt * 16 + lr) * ZLD + kk * 32 + cbase);
            a1 = __builtin_amdgcn_mfma_f32_16x16x32_bf16(afrag[kk], zfrag, a1, 0, 0, 0);
        }
        // D: col=lr -> v_local, row=lg*4+r -> a_local => lane holds
        // Y[v=mt*16+lr][a=w*16+lg*4+r], 4 consecutive a => b64 store.
        bf16x4 yv;
        #pragma unroll
        for (int r = 0; r < 4; ++r) yv[r] = (bf16)a1[r];
        *(bf16x4*)(Ysb + (mt * 16 + lr) * YLD + w * 16 + lg * 4) = yv;
    }
}

// W loaded inside the kk-loop (L2-hot, transient 16 regs — no prefetch array).
__device__ __forceinline__ void gemm2_acc(const bf16* Wq, const bf16* Ysb,
                                          f32x4 acc2[4][2], int lr, int cbase) {
    #pragma unroll
    for (int kk = 0; kk < 4; ++kk) {
        bf16x8 wf0 = *(const bf16x8*)(Wq + kk * 32 + cbase);
        bf16x8 wf1 = *(const bf16x8*)(Wq + 16 * QT + kk * 32 + cbase);
        #pragma unroll
        for (int mt = 0; mt < 4; ++mt) {
            bf16x8 af = *(const bf16x8*)(Ysb + (mt * 16 + lr) * YLD + kk * 32 + cbase);
            acc2[mt][0] = __builtin_amdgcn_mfma_f32_16x16x32_bf16(af, wf0, acc2[mt][0], 0, 0, 0);
            acc2[mt][1] = __builtin_amdgcn_mfma_f32_16x16x32_bf16(af, wf1, acc2[mt][1], 0, 0, 0);
        }
    }
}

// 5-barrier pipeline: region(q) = GEMM2(q-1) || GEMM1(q) || build(q+1).
// rsi double-buffered, Ys ping-pong; hazards one region apart (see bars).
__launch_bounds__(512, 4)
__global__ void featkhop(const float* __restrict__ xg,
                         const float* __restrict__ ng,
                         const bf16* __restrict__ Wbf,
                         float* __restrict__ out) {
    // Zs rows 0..48 = x + 48 neighbors (bf16); rows 49..63 read by MFMA as
    // don't-care garbage (output rows discarded); f32 scratch aliases that
    // tail (3072 B of 4080 B), all barrier-ordered.
    __shared__ __align__(16) bf16 Zs[64 * ZLD];       // 17408 B
    __shared__ __align__(16) bf16 Ys[2][64 * YLD];    // 34816 B, ping-pong
    float* const xls  = (float*)(Zs + 49 * ZLD);      // 128 f32 (byte 13328, 16B-aligned)
    float* const sls  = xls + F;                       // [3][128] f32
    float* const rsi0 = xls + 4 * F;                   // 128 f32
    float* const rsi1 = xls + 5 * F;                   // 128 f32

    const int i = blockIdx.x;
    const int t = threadIdx.x;
    const int lane = t & 63;
    const int w = t >> 6;        // wave 0..7
    const int lr = lane & 15;
    const int lg = lane >> 4;

    // ---- stage x: fp32 to xls, bf16 to Z row 0 ----
    if (t < F / 4) {
        float4 v = *(const float4*)(xg + (size_t)i * F + t * 4);
        *(float4*)(xls + t * 4) = v;
        *(bf16x4*)(Zs + 0 * ZLD + t * 4) = cvt4(v);
    }
    // ---- stage neighbors: bf16 rows 1..48 ----
    const float* nb = ng + (size_t)i * (KH * NNBR * F);
    {
        #pragma unroll
        for (int c = 0; c < 3; ++c) {
            int j = c * 512 + t;
            float4 v = *(const float4*)(nb + j * 4);
            int fl = j * 4;
            int row = 1 + (fl >> 7);     // neighbor 0..47 -> rows 1..48
            int b = fl & 127;
            *(bf16x4*)(Zs + row * ZLD + b) = cvt4(v);
        }
    }
    // ---- s[q][b] from GLOBAL f32 (L2-hot; f32 summands -> absmax 0.0156) ----
    if (t < KH * F) {
        int q = t >> 7, b = t & 127;
        float s = 0.f;
        #pragma unroll
        for (int n = 0; n < NNBR; ++n) s += nb[(q * NNBR + n) * F + b];
        sls[q * F + b] = s;
    }
    __syncthreads();                     // bar S: Zs/xls/sls ready

    const int a_row = w * 16 + lr;
    const float x_a = xls[a_row];
    const int cbase = lg * 8;
    const bf16* Wbase = Wbf + (size_t)(w * 32 + lr) * QT;

    f32x4 acc2[4][2];
    {
        f32x4 zf = {0.f, 0.f, 0.f, 0.f};
        #pragma unroll
        for (int mt = 0; mt < 4; ++mt) { acc2[mt][0] = zf; acc2[mt][1] = zf; }
    }

    bf16x8 uvh[4];

    // ---- prologue: build(0) ----
    build_row(0, xls, sls, rsi0, uvh, x_a, a_row, cbase, lg);
    __syncthreads();                     // bar P: rsi0 ready

    // ---- region 0: GEMM1(0) ; build(1) ----
    gemm1_store(uvh, rsi0, Zs, Ys[0], lr, lg, w, cbase);
    build_row(1, xls, sls, rsi1, uvh, x_a, a_row, cbase, lg);
    __syncthreads();                     // bar 0: Ys[0] + rsi1 ready

    // ---- region 1: GEMM2(0) ; GEMM1(1) ; build(2) ----
    // rsi0 rewrite is safe: its readers (GEMM1(0)) finished before bar 0.
    gemm2_acc(Wbase + 0 * F, Ys[0], acc2, lr, cbase);
    gemm1_store(uvh, rsi1, Zs, Ys[1], lr, lg, w, cbase);
    build_row(2, xls, sls, rsi0, uvh, x_a, a_row, cbase, lg);
    __syncthreads();                     // bar 1: Ys[1] + rsi0(q2) ready

    // ---- region 2: GEMM2(1) ; GEMM1(2) ----
    // Ys[0] rewrite safe: its readers (GEMM2(0)) finished before bar 1.
    gemm2_acc(Wbase + 1 * F, Ys[1], acc2, lr, cbase);
    gemm1_store(uvh, rsi0, Zs, Ys[0], lr, lg, w, cbase);
    __syncthreads();                     // bar 2: Ys[0](q2) ready

    // ---- tail: GEMM2(2) ----
    gemm2_acc(Wbase + 2 * F, Ys[0], acc2, lr, cbase);

    // ---- epilogue: row 0 -> x_out, rows 1..48 -> nbr_out ----
    float* xout = out + (size_t)i * OUT_O;
    float* nout = out + (size_t)NSAMP * OUT_O + (size_t)i * 48 * OUT_O;
    #pragma unroll
    for (int mt = 0; mt < 4; ++mt) {
        #pragma unroll
        for (int r = 0; r < 4; ++r) {
            int v = mt * 16 + lg * 4 + r;
            #pragma unroll
            for (int nn = 0; nn < 2; ++nn) {
                int o = w * 32 + nn * 16 + lr;
                float val = acc2[mt][nn][r];
                if (v == 0) xout[o] = val;
                else if (v <= 48) nout[(size_t)(v - 1) * OUT_O + o] = val;
            }
        }
    }
}

extern "C" void kernel_launch(void* const* d_in, const int* in_sizes, int n_in,
                              void* d_out, int out_size, void* d_ws, size_t ws_size,
                              hipStream_t stream) {
    const float* x   = (const float*)d_in[0];
    const float* nbr = (const float*)d_in[1];
    const float* W   = (const float*)d_in[2];
    bf16* Wbf = (bf16*)d_ws;   // 256*384 bf16 = 192 KiB
    wprep<<<(OUT_O * QT + 255) / 256, 256, 0, stream>>>(W, Wbf);
    featkhop<<<NSAMP, 512, 0, stream>>>(x, nbr, Wbf, (float*)d_out);
}